// Round 1
// baseline (246.756 us; speedup 1.0000x reference)
//
#include <hip/hip_runtime.h>

#define NBINS 1001
#define HIST_BLOCK 256
#define VPT 8                                     // float4s of x (and of y) per thread
#define ELEMS_PER_BLOCK (HIST_BLOCK * VPT * 4)    // 8192 -> 2048 blocks

typedef float fvec4 __attribute__((ext_vector_type(4)));   // clang vector: ok for nontemporal builtins

__device__ __forceinline__ int bin_of(float v) {
    // idx = #{ j in [0,999] : fp32(j/999) < v } ~= clamp(ceil(999*v), 0, 1000)
    // fp32 rounding flips a bin only when 999*v is within ~6e-5 of an integer
    // (~1e3 of 16.7M elems); each flip moves F1 by ~1e-6 << 1.08e-2 tolerance.
    int k = (int)ceilf(v * 999.0f);
    k = (k < 0) ? 0 : k;
    k = (k > 1000) ? 1000 : k;
    return k;
}

// Fused hist + F1: the histogram phase is unchanged from the 147.2 µs kernel
// (loads issued before the LDS-init barrier, packed u32 bins, one LDS atomic
// per element). The standalone f1_kernel launch is replaced by the canonical
// last-block-done pattern: ticket counter at ghist[4*NBINS] (zeroed by the
// same memset), release fence before the ticket, last block computes F1 with
// its 256 threads via agent-scope loads (per-XCD L2 non-coherence, G16).
__global__ __launch_bounds__(HIST_BLOCK) void hist_f1_kernel(
    const float* __restrict__ x, const float* __restrict__ y,
    unsigned long long* __restrict__ ghist, float* __restrict__ out, int HW)
{
    __shared__ unsigned int lh[NBINS];
    const int tid = threadIdx.x;

    const long long start = (long long)blockIdx.x * ELEMS_PER_BLOCK;
    const int c = (int)((start / HW) & 3);   // 8192 | HW=262144: block is class-uniform

    const fvec4* __restrict__ x4 = (const fvec4*)(x + start);
    const fvec4* __restrict__ y4 = (const fvec4*)(y + start);

    // Issue the whole memory phase first (single-use data -> nontemporal).
    fvec4 xv[VPT], yv[VPT];
    #pragma unroll
    for (int k = 0; k < VPT; ++k) {
        const int idx = k * HIST_BLOCK + tid;    // lanes contiguous: coalesced
        xv[k] = __builtin_nontemporal_load(&x4[idx]);
        yv[k] = __builtin_nontemporal_load(&y4[idx]);
    }

    // LDS init + barrier overlap the in-flight loads.
    for (int i = tid; i < NBINS; i += HIST_BLOCK) lh[i] = 0u;
    __syncthreads();

    #pragma unroll
    for (int k = 0; k < VPT; ++k) {
        // y is exactly 0.0f or 1.0f: bits(1.0f)=0x3f800000 -> (>>8)&0x10000
        atomicAdd(&lh[bin_of(xv[k].x)], 1u + ((__float_as_uint(yv[k].x) >> 8) & 0x10000u));
        atomicAdd(&lh[bin_of(xv[k].y)], 1u + ((__float_as_uint(yv[k].y) >> 8) & 0x10000u));
        atomicAdd(&lh[bin_of(xv[k].z)], 1u + ((__float_as_uint(yv[k].z) >> 8) & 0x10000u));
        atomicAdd(&lh[bin_of(xv[k].w)], 1u + ((__float_as_uint(yv[k].w) >> 8) & 0x10000u));
    }
    __syncthreads();

    // Flush: unpack u32 -> u64 (low32 = count, high32 = positive count)
    for (int i = tid; i < NBINS; i += HIST_BLOCK) {
        unsigned int v = lh[i];
        if (v) {
            unsigned long long add = (unsigned long long)(v & 0xffffu)
                                   | ((unsigned long long)(v >> 16) << 32);
            atomicAdd(&ghist[(size_t)c * NBINS + i], add);
        }
    }

    // ---- last-block-done handoff ----
    // __syncthreads() drains the flush atomics (compiler emits s_waitcnt
    // vmcnt(0) before s_barrier); then thread 0 publishes with a device-scope
    // release fence + ticket add.
    __syncthreads();
    __shared__ unsigned long long s_done;
    if (tid == 0) {
        __threadfence();   // release: our flush atomics are globally visible
        s_done = atomicAdd(&ghist[(size_t)4 * NBINS], 1ULL);
    }
    __syncthreads();
    if (s_done != (unsigned long long)(gridDim.x - 1)) return;

    // ===== last block: F1 reduction over 4 classes x 1001 bins =====
    __threadfence();   // acquire side
    __shared__ unsigned long long wscan[4];
    __shared__ float wmax[4];
    const int lane = tid & 63;
    const int wave = tid >> 6;

    float loss = 0.0f;   // meaningful on tid 0 only
    for (int cc = 0; cc < 4; ++cc) {
        // thread t owns bins 4t .. 4t+3 (1024 slots cover 1001 bins)
        unsigned long long inc[4];
        unsigned long long run = 0;
        #pragma unroll
        for (int j = 0; j < 4; ++j) {
            const int bin = 4 * tid + j;
            unsigned long long b = 0;
            if (bin < NBINS)
                b = __hip_atomic_load(&ghist[(size_t)cc * NBINS + bin],
                                      __ATOMIC_RELAXED, __HIP_MEMORY_SCOPE_AGENT);
            run += b;
            inc[j] = run;   // inclusive prefix within thread
        }
        const unsigned long long tsum = run;

        // wave-inclusive scan of per-thread sums (packed fields can't interact)
        unsigned long long sc = tsum;
        #pragma unroll
        for (int off = 1; off < 64; off <<= 1) {
            unsigned long long t = __shfl_up(sc, off, 64);
            if (lane >= off) sc += t;
        }
        if (lane == 63) wscan[wave] = sc;
        __syncthreads();

        unsigned long long woff = 0;
        #pragma unroll
        for (int w = 0; w < 4; ++w)
            if (w < wave) woff += wscan[w];
        const unsigned long long tot = wscan[0] + wscan[1] + wscan[2] + wscan[3];
        const unsigned long long base = woff + sc - tsum;  // exclusive prefix

        const unsigned int total_cnt = (unsigned int)(tot & 0xffffffffULL);
        const unsigned int total_y   = (unsigned int)(tot >> 32);

        float m = 0.0f;
        #pragma unroll
        for (int j = 0; j < 4; ++j) {
            const int bin = 4 * tid + j;
            if (bin < NBINS - 1) {   // thresholds k = 0..999
                const unsigned long long cum = base + inc[j];
                const unsigned int cnt_cum = (unsigned int)(cum & 0xffffffffULL);
                const unsigned int y_cum   = (unsigned int)(cum >> 32);
                const unsigned int TP = total_y - y_cum;
                const unsigned int PP = total_cnt - cnt_cum;
                const unsigned int denom = total_y + PP;  // = 2*(TP + 0.5*(FN+FP))
                const float f1 = (denom == 0u) ? 0.0f : (2.0f * (float)TP) / (float)denom;
                m = fmaxf(m, f1);
            }
        }
        // wave max-reduce, then cross-wave via LDS
        #pragma unroll
        for (int off = 32; off > 0; off >>= 1)
            m = fmaxf(m, __shfl_down(m, off, 64));
        if (lane == 0) wmax[wave] = m;
        __syncthreads();
        if (tid == 0)
            loss += 1.0f - fmaxf(fmaxf(wmax[0], wmax[1]), fmaxf(wmax[2], wmax[3]));
        __syncthreads();   // wscan/wmax reused next class
    }
    if (tid == 0) out[0] = loss * 0.25f;
}

extern "C" void kernel_launch(void* const* d_in, const int* in_sizes, int n_in,
                              void* d_out, int out_size, void* d_ws, size_t ws_size,
                              hipStream_t stream) {
    const float* x = (const float*)d_in[0];
    const float* y = (const float*)d_in[1];
    float* out = (float*)d_out;

    const int H = 512, W = 512;
    const int HW = H * W;
    const long long total = (long long)in_sizes[0];   // 16777216

    unsigned long long* ghist = (unsigned long long*)d_ws;

    // 4*NBINS bins + 1 ticket counter, all zeroed (workspace is re-poisoned
    // between iterations, so this memset is mandatory every call).
    (void)hipMemsetAsync(d_ws, 0, (size_t)(4 * NBINS + 1) * sizeof(unsigned long long), stream);

    const int nblocks = (int)(total / ELEMS_PER_BLOCK);  // 2048
    hist_f1_kernel<<<nblocks, HIST_BLOCK, 0, stream>>>(x, y, ghist, out, HW);
    (void)n_in; (void)out_size; (void)ws_size;
}

// Round 2
// 146.851 us; speedup vs baseline: 1.6803x; 1.6803x over previous
//
#include <hip/hip_runtime.h>

#define NBINS 1001
#define HIST_BLOCK 256
#define VPT 8                                     // float4s of x (and of y) per thread
#define ELEMS_PER_BLOCK (HIST_BLOCK * VPT * 4)    // 8192 -> 2048 blocks

typedef float fvec4 __attribute__((ext_vector_type(4)));   // clang vector: ok for nontemporal builtins

__device__ __forceinline__ int bin_of(float v) {
    // idx = #{ j in [0,999] : fp32(j/999) < v } ~= clamp(ceil(999*v), 0, 1000)
    // fp32 rounding flips a bin only when 999*v is within ~6e-5 of an integer
    // (~1e3 of 16.7M elems); each flip moves F1 by ~1e-6 << 1.08e-2 tolerance.
    int k = (int)ceilf(v * 999.0f);
    k = (k < 0) ? 0 : k;
    k = (k > 1000) ? 1000 : k;
    return k;
}

// REVERT of the round-1 single-kernel fusion. Post-mortem: fusing the F1
// tail dropped VGPR_Count to 36 (< the 64 VGPRs needed to keep all 16
// nontemporal float4 loads in flight), and the post-flush
// __syncthreads+__threadfence+ticket put the contended global-atomic drain
// (plus 2048 device-scope L2-writeback fences, WRITE_SIZE 16.4 MB -> HBM)
// on every block's critical path: 135 us, VALUBusy 2.8%, 620 GB/s.
// This two-kernel version measured 147.2/147.7 us with hist < 40 us.
//
// Phase-overlap structure: ALL 16 nontemporal loads issued before the LDS
// init barrier (16 KB outstanding per wave through the barrier), then the
// atomic phase runs while other waves' loads are still in flight.
// Packed u32 bins: low16 = count, high16 = positive count (block sees 8192
// elems -> no overflow). One LDS atomic per element is the scatter minimum.
__global__ __launch_bounds__(HIST_BLOCK) void hist_kernel(
    const float* __restrict__ x, const float* __restrict__ y,
    unsigned long long* __restrict__ ghist, int HW)
{
    __shared__ unsigned int lh[NBINS];
    const int tid = threadIdx.x;

    const long long start = (long long)blockIdx.x * ELEMS_PER_BLOCK;
    const int c = (int)((start / HW) & 3);   // 8192 | HW=262144: block is class-uniform

    const fvec4* __restrict__ x4 = (const fvec4*)(x + start);
    const fvec4* __restrict__ y4 = (const fvec4*)(y + start);

    // Issue the whole memory phase first (single-use data -> nontemporal).
    fvec4 xv[VPT], yv[VPT];
    #pragma unroll
    for (int k = 0; k < VPT; ++k) {
        const int idx = k * HIST_BLOCK + tid;    // lanes contiguous: coalesced
        xv[k] = __builtin_nontemporal_load(&x4[idx]);
        yv[k] = __builtin_nontemporal_load(&y4[idx]);
    }

    // LDS init + barrier overlap the in-flight loads.
    for (int i = tid; i < NBINS; i += HIST_BLOCK) lh[i] = 0u;
    __syncthreads();

    #pragma unroll
    for (int k = 0; k < VPT; ++k) {
        // y is exactly 0.0f or 1.0f: bits(1.0f)=0x3f800000 -> (>>8)&0x10000
        atomicAdd(&lh[bin_of(xv[k].x)], 1u + ((__float_as_uint(yv[k].x) >> 8) & 0x10000u));
        atomicAdd(&lh[bin_of(xv[k].y)], 1u + ((__float_as_uint(yv[k].y) >> 8) & 0x10000u));
        atomicAdd(&lh[bin_of(xv[k].z)], 1u + ((__float_as_uint(yv[k].z) >> 8) & 0x10000u));
        atomicAdd(&lh[bin_of(xv[k].w)], 1u + ((__float_as_uint(yv[k].w) >> 8) & 0x10000u));
    }
    __syncthreads();

    // Flush: unpack u32 -> u64 (low32 = count, high32 = positive count).
    // Fire-and-forget atomics: waves retire with them in flight; completion
    // overlaps across blocks at dispatch level (do NOT add a trailing sync).
    for (int i = tid; i < NBINS; i += HIST_BLOCK) {
        unsigned int v = lh[i];
        if (v) {
            unsigned long long add = (unsigned long long)(v & 0xffffu)
                                   | ((unsigned long long)(v >> 16) << 32);
            atomicAdd(&ghist[(size_t)c * NBINS + i], add);
        }
    }
}

// One block, 1024 threads; thread t owns bin t for all 4 classes.
__global__ __launch_bounds__(1024) void f1_kernel(
    const unsigned long long* __restrict__ ghist, float* __restrict__ out)
{
    __shared__ unsigned long long wtot[4][16];
    __shared__ float wmax[4][16];
    const int tid  = threadIdx.x;
    const int lane = tid & 63;
    const int wave = tid >> 6;

    unsigned long long v[4];
    #pragma unroll
    for (int c = 0; c < 4; ++c)
        v[c] = (tid < NBINS) ? ghist[(size_t)c * NBINS + tid] : 0ULL;

    // intra-wave inclusive scan (u64, packed cnt | ycnt<<32 - fields can't interact)
    #pragma unroll
    for (int off = 1; off < 64; off <<= 1) {
        #pragma unroll
        for (int c = 0; c < 4; ++c) {
            unsigned long long t = __shfl_up(v[c], off, 64);
            if (lane >= off) v[c] += t;
        }
    }
    if (lane == 63) {
        #pragma unroll
        for (int c = 0; c < 4; ++c) wtot[c][wave] = v[c];
    }
    __syncthreads();

    // wave 0: inclusive scan of the 16 wave totals per class (lane = c*16 + w)
    if (wave == 0) {
        const int c = lane >> 4, w = lane & 15;
        unsigned long long t = wtot[c][w];
        #pragma unroll
        for (int off = 1; off < 16; off <<= 1) {
            unsigned long long s = __shfl_up(t, off, 16);
            if (w >= off) t += s;
        }
        wtot[c][w] = t;
    }
    __syncthreads();

    float m[4];
    #pragma unroll
    for (int c = 0; c < 4; ++c) {
        unsigned long long cum = v[c];
        if (wave > 0) cum += wtot[c][wave - 1];
        unsigned long long tot = wtot[c][15];
        unsigned int total_cnt = (unsigned int)(tot & 0xffffffffULL);  // N per class
        unsigned int total_y   = (unsigned int)(tot >> 32);
        float f1 = 0.0f;
        if (tid < NBINS - 1) {  // thresholds k = 0..999
            unsigned int cnt_cum = (unsigned int)(cum & 0xffffffffULL);
            unsigned int y_cum   = (unsigned int)(cum >> 32);
            unsigned int TP = total_y - y_cum;
            unsigned int PP = total_cnt - cnt_cum;
            unsigned int denom = total_y + PP;  // = 2*(TP + 0.5*(FN+FP))
            f1 = (denom == 0u) ? 0.0f : (2.0f * (float)TP) / (float)denom;
        }
        m[c] = f1;
    }

    // wave max-reduce per class
    #pragma unroll
    for (int off = 32; off > 0; off >>= 1) {
        #pragma unroll
        for (int c = 0; c < 4; ++c)
            m[c] = fmaxf(m[c], __shfl_down(m[c], off, 64));
    }
    if (lane == 0) {
        #pragma unroll
        for (int c = 0; c < 4; ++c) wmax[c][wave] = m[c];
    }
    __syncthreads();

    if (tid == 0) {
        float loss = 0.0f;
        #pragma unroll
        for (int c = 0; c < 4; ++c) {
            float mm = wmax[c][0];
            #pragma unroll
            for (int w = 1; w < 16; ++w) mm = fmaxf(mm, wmax[c][w]);
            loss += 1.0f - mm;
        }
        out[0] = loss * 0.25f;
    }
}

extern "C" void kernel_launch(void* const* d_in, const int* in_sizes, int n_in,
                              void* d_out, int out_size, void* d_ws, size_t ws_size,
                              hipStream_t stream) {
    const float* x = (const float*)d_in[0];
    const float* y = (const float*)d_in[1];
    float* out = (float*)d_out;

    const int H = 512, W = 512;
    const int HW = H * W;
    const long long total = (long long)in_sizes[0];   // 16777216

    unsigned long long* ghist = (unsigned long long*)d_ws;

    (void)hipMemsetAsync(d_ws, 0, (size_t)4 * NBINS * sizeof(unsigned long long), stream);

    const int nblocks = (int)(total / ELEMS_PER_BLOCK);  // 2048
    hist_kernel<<<nblocks, HIST_BLOCK, 0, stream>>>(x, y, ghist, HW);
    f1_kernel<<<1, 1024, 0, stream>>>(ghist, out);
    (void)n_in; (void)out_size; (void)ws_size;
}

// Round 3
// 144.563 us; speedup vs baseline: 1.7069x; 1.0158x over previous
//
#include <hip/hip_runtime.h>

#define NBINS 1001
#define HIST_BLOCK 256
#define VPT 8                                     // float4s of x (and of y) per thread per tile
#define TILES 2
#define TILE_ELEMS (HIST_BLOCK * VPT * 4)         // 8192
#define ELEMS_PER_BLOCK (TILE_ELEMS * TILES)      // 16384 -> 1024 blocks

typedef float fvec4 __attribute__((ext_vector_type(4)));   // clang vector: ok for nontemporal builtins

__device__ __forceinline__ int bin_of(float v) {
    // idx = #{ j in [0,999] : fp32(j/999) < v } ~= clamp(ceil(999*v), 0, 1000)
    // fp32 rounding flips a bin only when 999*v is within ~6e-5 of an integer
    // (~1e3 of 16.7M elems); each flip moves F1 by ~1e-6 << 1.08e-2 tolerance.
    int k = (int)ceilf(v * 999.0f);
    k = (k < 0) ? 0 : k;
    k = (k > 1000) ? 1000 : k;
    return k;
}

// Round-3 change vs the verified 147 µs kernel: 1024 blocks x 16384 elems
// (2 tiles of the same VPT=8 register set) instead of 2048 x 8192.
//   - grid fits residency in ONE dispatch round (1024/256CU = 4 blocks/CU at
//     ~100 VGPR -> no second-round latency ramp / tail)
//   - flush atomics halved: 2.05M -> 1.02M u64 RMWs onto the same 500 lines
//   - per-block LDS-init/flush fixed cost halved
// Tile-1 loads are issued interleaved with tile-0's LDS atomics (each reg
// slot reloaded right after its last use) so the load pipeline never drains.
// Packed u32 bins: low16 = count, high16 = positive count; worst case
// 16384 < 65536 per field -> no overflow. Histogram bit-identical.
__global__ __launch_bounds__(HIST_BLOCK) void hist_kernel(
    const float* __restrict__ x, const float* __restrict__ y,
    unsigned long long* __restrict__ ghist, int HW)
{
    __shared__ unsigned int lh[NBINS];
    const int tid = threadIdx.x;

    const long long start = (long long)blockIdx.x * ELEMS_PER_BLOCK;
    const int c = (int)((start / HW) & 3);   // 16384 | HW=262144: block is class-uniform

    const fvec4* __restrict__ x4 = (const fvec4*)(x + start);
    const fvec4* __restrict__ y4 = (const fvec4*)(y + start);

    // Issue tile 0's whole memory phase first (single-use data -> nontemporal).
    fvec4 xv[VPT], yv[VPT];
    #pragma unroll
    for (int k = 0; k < VPT; ++k) {
        const int idx = k * HIST_BLOCK + tid;    // lanes contiguous: coalesced
        xv[k] = __builtin_nontemporal_load(&x4[idx]);
        yv[k] = __builtin_nontemporal_load(&y4[idx]);
    }

    // LDS init + barrier overlap the in-flight loads.
    for (int i = tid; i < NBINS; i += HIST_BLOCK) lh[i] = 0u;
    __syncthreads();

    #pragma unroll
    for (int t = 0; t < TILES; ++t) {
        #pragma unroll
        for (int k = 0; k < VPT; ++k) {
            const fvec4 xa = xv[k], ya = yv[k];
            if (t + 1 < TILES) {
                // reload this slot for the next tile; load latency hides
                // under the remaining atomics of the current tile
                const int idx = (t + 1) * (VPT * HIST_BLOCK) + k * HIST_BLOCK + tid;
                xv[k] = __builtin_nontemporal_load(&x4[idx]);
                yv[k] = __builtin_nontemporal_load(&y4[idx]);
            }
            // y is exactly 0.0f or 1.0f: bits(1.0f)=0x3f800000 -> (>>8)&0x10000
            atomicAdd(&lh[bin_of(xa.x)], 1u + ((__float_as_uint(ya.x) >> 8) & 0x10000u));
            atomicAdd(&lh[bin_of(xa.y)], 1u + ((__float_as_uint(ya.y) >> 8) & 0x10000u));
            atomicAdd(&lh[bin_of(xa.z)], 1u + ((__float_as_uint(ya.z) >> 8) & 0x10000u));
            atomicAdd(&lh[bin_of(xa.w)], 1u + ((__float_as_uint(ya.w) >> 8) & 0x10000u));
        }
    }
    __syncthreads();

    // Flush: unpack u32 -> u64 (low32 = count, high32 = positive count).
    // Fire-and-forget atomics: waves retire with them in flight; completion
    // overlaps across blocks at dispatch level (do NOT add a trailing sync).
    for (int i = tid; i < NBINS; i += HIST_BLOCK) {
        unsigned int v = lh[i];
        if (v) {
            unsigned long long add = (unsigned long long)(v & 0xffffu)
                                   | ((unsigned long long)(v >> 16) << 32);
            atomicAdd(&ghist[(size_t)c * NBINS + i], add);
        }
    }
}

// One block, 1024 threads; thread t owns bin t for all 4 classes.
__global__ __launch_bounds__(1024) void f1_kernel(
    const unsigned long long* __restrict__ ghist, float* __restrict__ out)
{
    __shared__ unsigned long long wtot[4][16];
    __shared__ float wmax[4][16];
    const int tid  = threadIdx.x;
    const int lane = tid & 63;
    const int wave = tid >> 6;

    unsigned long long v[4];
    #pragma unroll
    for (int c = 0; c < 4; ++c)
        v[c] = (tid < NBINS) ? ghist[(size_t)c * NBINS + tid] : 0ULL;

    // intra-wave inclusive scan (u64, packed cnt | ycnt<<32 - fields can't interact)
    #pragma unroll
    for (int off = 1; off < 64; off <<= 1) {
        #pragma unroll
        for (int c = 0; c < 4; ++c) {
            unsigned long long t = __shfl_up(v[c], off, 64);
            if (lane >= off) v[c] += t;
        }
    }
    if (lane == 63) {
        #pragma unroll
        for (int c = 0; c < 4; ++c) wtot[c][wave] = v[c];
    }
    __syncthreads();

    // wave 0: inclusive scan of the 16 wave totals per class (lane = c*16 + w)
    if (wave == 0) {
        const int c = lane >> 4, w = lane & 15;
        unsigned long long t = wtot[c][w];
        #pragma unroll
        for (int off = 1; off < 16; off <<= 1) {
            unsigned long long s = __shfl_up(t, off, 16);
            if (w >= off) t += s;
        }
        wtot[c][w] = t;
    }
    __syncthreads();

    float m[4];
    #pragma unroll
    for (int c = 0; c < 4; ++c) {
        unsigned long long cum = v[c];
        if (wave > 0) cum += wtot[c][wave - 1];
        unsigned long long tot = wtot[c][15];
        unsigned int total_cnt = (unsigned int)(tot & 0xffffffffULL);  // N per class
        unsigned int total_y   = (unsigned int)(tot >> 32);
        float f1 = 0.0f;
        if (tid < NBINS - 1) {  // thresholds k = 0..999
            unsigned int cnt_cum = (unsigned int)(cum & 0xffffffffULL);
            unsigned int y_cum   = (unsigned int)(cum >> 32);
            unsigned int TP = total_y - y_cum;
            unsigned int PP = total_cnt - cnt_cum;
            unsigned int denom = total_y + PP;  // = 2*(TP + 0.5*(FN+FP))
            f1 = (denom == 0u) ? 0.0f : (2.0f * (float)TP) / (float)denom;
        }
        m[c] = f1;
    }

    // wave max-reduce per class
    #pragma unroll
    for (int off = 32; off > 0; off >>= 1) {
        #pragma unroll
        for (int c = 0; c < 4; ++c)
            m[c] = fmaxf(m[c], __shfl_down(m[c], off, 64));
    }
    if (lane == 0) {
        #pragma unroll
        for (int c = 0; c < 4; ++c) wmax[c][wave] = m[c];
    }
    __syncthreads();

    if (tid == 0) {
        float loss = 0.0f;
        #pragma unroll
        for (int c = 0; c < 4; ++c) {
            float mm = wmax[c][0];
            #pragma unroll
            for (int w = 1; w < 16; ++w) mm = fmaxf(mm, wmax[c][w]);
            loss += 1.0f - mm;
        }
        out[0] = loss * 0.25f;
    }
}

extern "C" void kernel_launch(void* const* d_in, const int* in_sizes, int n_in,
                              void* d_out, int out_size, void* d_ws, size_t ws_size,
                              hipStream_t stream) {
    const float* x = (const float*)d_in[0];
    const float* y = (const float*)d_in[1];
    float* out = (float*)d_out;

    const int H = 512, W = 512;
    const int HW = H * W;
    const long long total = (long long)in_sizes[0];   // 16777216

    unsigned long long* ghist = (unsigned long long*)d_ws;

    (void)hipMemsetAsync(d_ws, 0, (size_t)4 * NBINS * sizeof(unsigned long long), stream);

    const int nblocks = (int)(total / ELEMS_PER_BLOCK);  // 1024
    hist_kernel<<<nblocks, HIST_BLOCK, 0, stream>>>(x, y, ghist, HW);
    f1_kernel<<<1, 1024, 0, stream>>>(ghist, out);
    (void)n_in; (void)out_size; (void)ws_size;
}